// Round 1
// 178.764 us; speedup vs baseline: 1.0629x; 1.0629x over previous
//
#include <hip/hip_runtime.h>
#include <hip/hip_bf16.h>

// VectorQuantize: B=4, N=2048, DIM=256, HEADS=4, CODEBOOK=8192, HD=64
// Established (R0-R10): inputs fp32, output fp32 (quantize ++ indices-as-floats).
// R10: fp16 2-level split, 3 MFMA terms, NPART=8, 139.6us dist / 190 total.
//   MfmaUtil 32, VALUBusy 41, bank-conflict 0. MFMA floor 50us -> ~90us exposed
//   stall. Static pipe accounting << wall => latency/arbitration-bound.
// R11 (this round):
//   (a) persistent-zero acc init (z4 as MFMA C operand) + fold ycn into the
//       epilogue add: removes 32 movs/inner AND the y2s ds_read->first-MFMA
//       dependency from every rt chain.
//   (b) s_setprio(1/0) around each 6-MFMA rt chain (T5; 4 independent
//       blocks/CU = role-diverse regime, not m190 lockstep).
//   (c) merge_kernel rewrite: 256 blocks; phase1 partition-merge + coalesced
//       idx store; phase2 wave-per-row gather (1KiB coalesced stores) -- old
//       version was 128 blocks with 16B-per-64B-line strided stores.

#define HEADS    4
#define CODEBOOK 8192
#define HD       64
#define BQ       8192                  // queries per head = B*N
#define QOFF     (4 * 2048 * 256)      // quantize FLOAT elements in d_out
#define NPART    8
#define CPART    (CODEBOOK / NPART)    // 1024 codes per partition
#define SCODES   64                    // codes per stage
#define NSTAGE   (CPART / SCODES)      // 16 stages
#define RSCALE   4096.0f               // residual scale (2^12)
#define RINV     (1.0f / 4096.0f)

typedef _Float16 f16x8 __attribute__((ext_vector_type(8)));
typedef float    f32x4 __attribute__((ext_vector_type(4)));

__device__ float g_pval[NPART][HEADS * BQ];       // per-partition best (max score)
__device__ int   g_pidx[NPART][HEADS * BQ];       // per-partition best index

// split fp32 -> 2 fp16 levels: f ~= (float)h0 + (float)h1 / 4096, |err|<=2^-24|f|
__device__ inline void split2(float f, _Float16& h0, _Float16& h1) {
    h0 = (_Float16)f;
    float r = f - (float)h0;
    h1 = (_Float16)(r * RSCALE);
}

// ---------------- kernel 1: split-fp16 MFMA scores + argmax ----------------
// grid = 1024 = head(4) x qgroup(32) x part(8); block = 256 (4 waves).
// Each wave owns 64 queries (4 pinned A row-tiles); block scans one 1024-code
// partition in 16 stages of 64 codes through double-buffered, XOR-swizzled LDS
// (conflict-free b128 write+read — verified R5/R8: SQ_LDS_BANK_CONFLICT == 0).
// y2 (= -0.5||e||^2) computed for free inside the staging path (R8-verified).
// MFMA 16x16x32_f16 layouts (same operand shape as bf16, HW-verified family):
//   A: lane -> A[m=lane&15][k=quad*8+j];  B: lane -> B[k=quad*8+j][n=lane&15]
//   C: lane -> col=lane&15, row=quad*4+reg
__global__ __launch_bounds__(256, 2) void dist_kernel(const float* __restrict__ x,
                                                      const float* __restrict__ embed) {
    __shared__ __align__(16) _Float16 tile[2][2][SCODES * 64];   // 32768 B
    __shared__ float y2s[CPART];                                 // 4096 B

    const int bid  = blockIdx.x;
    const int part = bid & 7;
    const int qg   = (bid >> 3) & 31;
    const int h    = bid >> 8;
    const int t    = threadIdx.x;
    const int wave = t >> 6;
    const int lane = t & 63;
    const int col  = lane & 15;
    const int quad = lane >> 4;

    const int qbase = qg * 256 + wave * 64;       // this wave's 64 queries
    const int cbase = part * CPART;

    // A fragments a[rowtile][level][khalf], split on the fly from fp32 x
    f16x8 a[4][2][2];
#pragma unroll
    for (int rt = 0; rt < 4; rt++) {
#pragma unroll
        for (int kh = 0; kh < 2; kh++) {
            const float* p = x + ((size_t)(qbase + rt * 16 + col) * 256 + h * 64 + kh * 32 + quad * 8);
#pragma unroll
            for (int j = 0; j < 8; j++) {
                _Float16 h0, h1;
                split2(p[j], h0, h1);
                a[rt][0][kh][j] = h0;
                a[rt][1][kh][j] = h1;
            }
        }
    }

    // staging: thread t owns rows (t>>3), (t>>3)+32, 8-float granule t&7
    const float* esrc = embed + ((size_t)h * CODEBOOK + cbase) * HD + (size_t)t * 8;
    const int row  = t >> 3;
    const int gsw  = (t & 7) ^ (row & 7);          // swizzled granule (same for row+32)
    const int ldA  = row * 64 + gsw * 8;           // f16 units within a level plane
    const int ldB  = (row + 32) * 64 + gsw * 8;

    float bv[4][4]; int bc[4][4];
#pragma unroll
    for (int rt = 0; rt < 4; rt++)
#pragma unroll
        for (int r = 0; r < 4; r++) { bv[rt][r] = -3.4e38f; bc[rt][r] = 0; }

    float4 pfA0, pfA1, pfB0, pfB1;                 // prefetch regs (2 rows x 8 floats)

    // split both rows -> 2 LDS planes of `buf`; also compute + publish -0.5*y2
    auto stage_write = [&](int buf, int stage) {
        float fA[8] = {pfA0.x, pfA0.y, pfA0.z, pfA0.w, pfA1.x, pfA1.y, pfA1.z, pfA1.w};
        float fB[8] = {pfB0.x, pfB0.y, pfB0.z, pfB0.w, pfB1.x, pfB1.y, pfB1.z, pfB1.w};
        f16x8 vA0, vA1, vB0, vB1;
        float ssA = 0.f, ssB = 0.f;
#pragma unroll
        for (int j = 0; j < 8; j++) {
            _Float16 h0, h1;
            split2(fA[j], h0, h1);
            vA0[j] = h0; vA1[j] = h1;
            ssA = fmaf(fA[j], fA[j], ssA);
            split2(fB[j], h0, h1);
            vB0[j] = h0; vB1[j] = h1;
            ssB = fmaf(fB[j], fB[j], ssB);
        }
        *reinterpret_cast<f16x8*>(&tile[buf][0][ldA]) = vA0;
        *reinterpret_cast<f16x8*>(&tile[buf][1][ldA]) = vA1;
        *reinterpret_cast<f16x8*>(&tile[buf][0][ldB]) = vB0;
        *reinterpret_cast<f16x8*>(&tile[buf][1][ldB]) = vB1;
#pragma unroll
        for (int off = 4; off >= 1; off >>= 1) {   // width-8 granule tree
            ssA += __shfl_xor(ssA, off, 8);
            ssB += __shfl_xor(ssB, off, 8);
        }
        if ((t & 7) == 0) {
            y2s[stage * SCODES + row]      = -0.5f * ssA;
            y2s[stage * SCODES + row + 32] = -0.5f * ssB;
        }
    };
    auto stage_load = [&](int stage) {
        const float* ps = esrc + (size_t)stage * (SCODES * HD);
        pfA0 = *reinterpret_cast<const float4*>(ps);
        pfA1 = *reinterpret_cast<const float4*>(ps + 4);
        pfB0 = *reinterpret_cast<const float4*>(ps + 32 * HD);
        pfB1 = *reinterpret_cast<const float4*>(ps + 32 * HD + 4);
    };

    // preamble: stage 0 staged + y2, stage 1 prefetched, publish
    stage_load(0);
    stage_write(0, 0);
    stage_load(1);
    __syncthreads();

    const int swbase = col & 7;                    // read-side swizzle key
    const f32x4 z4 = {0.f, 0.f, 0.f, 0.f};        // persistent zero C-operand

    for (int s = 0; s < NSTAGE; s++) {
        // write stage s+1 (+ its y2) into the other buffer, then issue load of
        // stage s+2; the in-flight load drains at THIS stage's end barrier.
        if (s + 1 < NSTAGE) stage_write((s + 1) & 1, s + 1);
        if (s + 2 < NSTAGE) stage_load(s + 2);

#pragma unroll
        for (int inner = 0; inner < 4; inner++) {
            const int rbase = (inner * 16 + col) * 64;     // row offset in plane
            f16x8 b[2][2];
#pragma unroll
            for (int lvl = 0; lvl < 2; lvl++)
#pragma unroll
                for (int kh = 0; kh < 2; kh++)
                    b[lvl][kh] = *reinterpret_cast<const f16x8*>(
                        &tile[s & 1][lvl][rbase + ((((kh << 2) | quad) ^ swbase) << 3)]);

            const int   c   = s * SCODES + inner * 16 + col;   // partition-local code
            const float ycn = y2s[c];                          // -0.5*||e_c||^2 (epilogue-only now)
#pragma unroll
            for (int rt = 0; rt < 4; rt++) {
                __builtin_amdgcn_s_setprio(1);
                f32x4 aA = __builtin_amdgcn_mfma_f32_16x16x32_f16(a[rt][0][0], b[0][0], z4, 0, 0, 0);
                f32x4 aB = __builtin_amdgcn_mfma_f32_16x16x32_f16(a[rt][0][0], b[1][0], z4, 0, 0, 0);
                aB = __builtin_amdgcn_mfma_f32_16x16x32_f16(a[rt][1][0], b[0][0], aB, 0, 0, 0);
                aA = __builtin_amdgcn_mfma_f32_16x16x32_f16(a[rt][0][1], b[0][1], aA, 0, 0, 0);
                aB = __builtin_amdgcn_mfma_f32_16x16x32_f16(a[rt][0][1], b[1][1], aB, 0, 0, 0);
                aB = __builtin_amdgcn_mfma_f32_16x16x32_f16(a[rt][1][1], b[0][1], aB, 0, 0, 0);
                __builtin_amdgcn_s_setprio(0);
#pragma unroll
                for (int r = 0; r < 4; r++) {
                    float sv = fmaf(aB[r], RINV, aA[r] + ycn); // xy - 0.5||e||^2
                    if (sv > bv[rt][r]) { bv[rt][r] = sv; bc[rt][r] = c; }
                }
            }
        }
        __syncthreads();
    }

    // reduce across 16 column slots; lexicographic (max val, min idx) =
    // np first-argmax tie-break
#pragma unroll
    for (int rt = 0; rt < 4; rt++) {
#pragma unroll
        for (int r = 0; r < 4; r++) {
            float v = bv[rt][r]; int c = bc[rt][r];
#pragma unroll
            for (int off = 8; off >= 1; off >>= 1) {
                float ov = __shfl_xor(v, off, 16); int oc = __shfl_xor(c, off, 16);
                if (ov > v || (ov == v && oc < c)) { v = ov; c = oc; }
            }
            if (col == 0) {
                int q = h * BQ + qbase + rt * 16 + quad * 4 + r;
                g_pval[part][q] = v; g_pidx[part][q] = cbase + c;
            }
        }
    }
}

// ---------------- kernel 2: merge partitions + gather + index write --------
// 256 blocks x 256 thr; block owns 32 output rows (m).
// phase 1 (t<128): merge 8 partitions for (m,h), write idx coalesced, park in LDS.
// phase 2: wave-per-row gather: 64 lanes cover the 256-float row -> 1KiB
// coalesced stores, 256B-contiguous reads per head segment.
__global__ __launch_bounds__(256) void merge_kernel(const float* __restrict__ embed,
                                                    float* __restrict__ out) {
    __shared__ int iw[32][4];
    const int t     = threadIdx.x;
    const int mbase = blockIdx.x * 32;

    if (t < 128) {
        const int ml = t >> 2;
        const int h  = t & 3;
        const int q  = h * BQ + mbase + ml;
        float bv = g_pval[0][q]; int bc = g_pidx[0][q];
#pragma unroll
        for (int p = 1; p < NPART; p++) {
            float v = g_pval[p][q]; int c = g_pidx[p][q];
            if (v > bv || (v == bv && c < bc)) { bv = v; bc = c; }
        }
        out[QOFF + (size_t)mbase * 4 + t] = (float)bc;   // == (mbase+ml)*4 + h
        iw[ml][h] = bc & (CODEBOOK - 1);                 // defensive in-range
    }
    __syncthreads();

    const int wave = t >> 6;
    const int lane = t & 63;
    const int h    = lane >> 4;                    // head segment of this lane
    const int off  = (lane & 15) * 4;              // offset within head (0..60)
#pragma unroll
    for (int i = 0; i < 8; i++) {
        const int r   = wave * 8 + i;
        const int m   = mbase + r;
        const int idx = iw[r][h];
        const float4 v = *reinterpret_cast<const float4*>(
            embed + ((size_t)h * CODEBOOK + idx) * HD + off);
        *reinterpret_cast<float4*>(out + (size_t)m * 256 + lane * 4) = v;
    }
}

extern "C" void kernel_launch(void* const* d_in, const int* in_sizes, int n_in,
                              void* d_out, int out_size, void* d_ws, size_t ws_size,
                              hipStream_t stream) {
    const float* x     = (const float*)d_in[0];
    const float* embed = (const float*)d_in[1];
    float*       out   = (float*)d_out;

    dist_kernel <<<1024, 256, 0, stream>>>(x, embed);
    merge_kernel<<<256,  256, 0, stream>>>(embed, out);
}